// Round 1
// baseline (647.069 us; speedup 1.0000x reference)
//
#include <hip/hip_runtime.h>

#define HW 48
#define GRID_PER_B (HW * HW)   // 2304

// ---------------------------------------------------------------------------
// Kernel 1: per-batch TPS fit (double-precision 12x12 solve, 2 RHS) + grid
// evaluation (f32, matching reference), storing (gx, gy) per (b,h,w).
// Also zero-inits the 8 per-batch sum accumulators in d_out.
// ---------------------------------------------------------------------------
__global__ void tps_grid_kernel(const float* __restrict__ geo,
                                float2* __restrict__ gxy,
                                float* __restrict__ sums)
{
    const int b = blockIdx.x;
    __shared__ float s_wx[9], s_wy[9], s_ax[3], s_ay[3], s_px[9], s_py[9];

    if (blockIdx.x == 0 && threadIdx.x < 8) sums[threadIdx.x] = 0.0f;

    if (threadIdx.x == 0) {
        const float srcx[9] = {0.f, 0.5f, 1.f, 0.f, 0.5f, 1.f, 0.f, 5.f, 1.f};
        const float srcy[9] = {0.f, 0.f,  0.f, 0.5f,0.5f, 0.5f,1.f, 1.f, 1.f};
        double dstx[9], dsty[9];
        double A[12][14];
        for (int r = 0; r < 12; ++r)
            for (int c = 0; c < 14; ++c) A[r][c] = 0.0;

        for (int k = 0; k < 9; ++k) {
            float mvx = geo[(b * 9 + k) * 2 + 0];
            float mvy = geo[(b * 9 + k) * 2 + 1];
            dstx[k] = (double)srcx[k] + (double)mvx;
            dsty[k] = (double)srcy[k] + (double)mvy;
            A[k][12] = -(double)mvx;   // delta_x = src - dst = -mv
            A[k][13] = -(double)mvy;
        }
        for (int r = 0; r < 9; ++r) {
            for (int c = 0; c < 9; ++c) {
                double dx = dstx[r] - dstx[c];
                double dy = dsty[r] - dsty[c];
                double rr = sqrt(dx * dx + dy * dy);
                A[r][c] = rr * rr * log(rr + 1e-6);
            }
            A[r][9] = 1.0; A[r][10] = dstx[r]; A[r][11] = dsty[r];
            A[9][r] = 1.0; A[10][r] = dstx[r]; A[11][r] = dsty[r];
        }
        // Gaussian elimination with partial pivoting, 2 RHS columns.
        for (int col = 0; col < 12; ++col) {
            int piv = col; double best = fabs(A[col][col]);
            for (int r = col + 1; r < 12; ++r) {
                double v = fabs(A[r][col]);
                if (v > best) { best = v; piv = r; }
            }
            if (piv != col)
                for (int c = col; c < 14; ++c) {
                    double t = A[col][c]; A[col][c] = A[piv][c]; A[piv][c] = t;
                }
            double inv = 1.0 / A[col][col];
            for (int r = col + 1; r < 12; ++r) {
                double f = A[r][col] * inv;
                for (int c = col + 1; c < 14; ++c) A[r][c] -= f * A[col][c];
            }
        }
        double thx[12], thy[12];
        for (int r = 11; r >= 0; --r) {
            double sx = A[r][12], sy = A[r][13];
            for (int c = r + 1; c < 12; ++c) {
                sx -= A[r][c] * thx[c];
                sy -= A[r][c] * thy[c];
            }
            thx[r] = sx / A[r][r];
            thy[r] = sy / A[r][r];
        }
        // w = theta[1:9]; w_full[0] = -sum(w); a = theta[9:12]
        double swx = 0.0, swy = 0.0;
        for (int k = 1; k < 9; ++k) { swx += thx[k]; swy += thy[k]; }
        s_wx[0] = (float)(-swx); s_wy[0] = (float)(-swy);
        for (int k = 1; k < 9; ++k) { s_wx[k] = (float)thx[k]; s_wy[k] = (float)thy[k]; }
        s_ax[0] = (float)thx[9]; s_ax[1] = (float)thx[10]; s_ax[2] = (float)thx[11];
        s_ay[0] = (float)thy[9]; s_ay[1] = (float)thy[10]; s_ay[2] = (float)thy[11];
        for (int k = 0; k < 9; ++k) { s_px[k] = (float)dstx[k]; s_py[k] = (float)dsty[k]; }
    }
    __syncthreads();

    for (int p = threadIdx.x; p < GRID_PER_B; p += blockDim.x) {
        int h = p / HW, w = p % HW;
        float x = (float)w * (1.0f / 47.0f);
        float y = (float)h * (1.0f / 47.0f);
        float zx = s_ax[0] + s_ax[1] * x + s_ax[2] * y;
        float zy = s_ay[0] + s_ay[1] * x + s_ay[2] * y;
        #pragma unroll
        for (int k = 0; k < 9; ++k) {
            float ddx = x - s_px[k], ddy = y - s_py[k];
            float r2 = ddx * ddx + ddy * ddy;
            float r  = sqrtf(r2);
            float u  = r2 * logf(r + 1e-6f);
            zx += s_wx[k] * u;
            zy += s_wy[k] * u;
        }
        gxy[b * GRID_PER_B + p] = make_float2((zx + x) * 47.0f, (zy + y) * 47.0f);
    }
}

// ---------------------------------------------------------------------------
// Kernel 2: out[b,j,i,h,w] = mask ? corr : 0, plus per-batch sum.
// One float4 of output per thread; corr is read ONLY where mask passes.
// 48^4/1024 = 5184 blocks per batch -> a block never straddles batches.
// ---------------------------------------------------------------------------
__global__ __launch_bounds__(256) void mask_apply_kernel(
    const float* __restrict__ corr,
    const float2* __restrict__ gxy,
    float* __restrict__ out,
    float* __restrict__ sums)
{
    const int e4 = blockIdx.x * 256 + threadIdx.x;
    const int e  = e4 * 4;

    int w  = e  % 48;
    int t1 = e  / 48;
    int h  = t1 % 48;
    int t2 = t1 / 48;
    int i  = t2 % 48;
    int t3 = t2 / 48;
    int j  = t3 % 48;
    int b  = t3 / 48;

    const float fi = (float)i, fj = (float)j;
    const float2* g = gxy + (b * GRID_PER_B + h * 48 + w);

    float vals[4];
    float lsum = 0.0f;
    #pragma unroll
    for (int c = 0; c < 4; ++c) {
        float2 gc = g[c];
        bool cond = (fabsf(fi - gc.x) <= 1.0f) && (fabsf(fj - gc.y) <= 1.0f);
        float v = 0.0f;
        if (cond) v = corr[e + c];
        vals[c] = v;
        lsum += v;
    }
    *reinterpret_cast<float4*>(out + e) =
        make_float4(vals[0], vals[1], vals[2], vals[3]);

    // block reduction -> one atomic per non-empty block
    for (int off = 32; off > 0; off >>= 1)
        lsum += __shfl_down(lsum, off, 64);
    __shared__ float part[4];
    const int lane = threadIdx.x & 63, wv = threadIdx.x >> 6;
    if (lane == 0) part[wv] = lsum;
    __syncthreads();
    if (threadIdx.x == 0) {
        float s = part[0] + part[1] + part[2] + part[3];
        if (s != 0.0f) atomicAdd(&sums[b], s);
    }
}

extern "C" void kernel_launch(void* const* d_in, const int* in_sizes, int n_in,
                              void* d_out, int out_size, void* d_ws, size_t ws_size,
                              hipStream_t stream)
{
    const float* geo  = (const float*)d_in[0];   // (B, 9, 2) f32
    const float* corr = (const float*)d_in[1];   // (B, 48, 48, 48, 48) f32

    const int B = in_sizes[0] / 18;              // 8
    const int N = in_sizes[1];                   // B * 48^4

    float*  out  = (float*)d_out;
    float*  sums = out + N;                      // last B elements of d_out
    float2* gxy  = (float2*)d_ws;                // B*2304 float2 = 147 KB

    hipLaunchKernelGGL(tps_grid_kernel, dim3(B), dim3(256), 0, stream,
                       geo, gxy, sums);

    const int nblocks = N / (256 * 4);           // 41472 for B=8
    hipLaunchKernelGGL(mask_apply_kernel, dim3(nblocks), dim3(256), 0, stream,
                       corr, gxy, out, sums);
}

// Round 7
// 339.850 us; speedup vs baseline: 1.9040x; 1.9040x over previous
//
#include <hip/hip_runtime.h>

#define HW 48
#define GRID_PER_B (HW * HW)   // 2304
#define CORR_PER_B (HW * HW * HW * HW)

typedef float f32x4 __attribute__((ext_vector_type(4)));

// ---------------------------------------------------------------------------
// Kernel 1: per-batch TPS fit in LDS (parallel f64 Gauss-Jordan w/ pivoting),
// grid evaluation (f32, matching reference), writes (gx,gy) to d_ws AND
// computes the per-batch masked sum via the sparse <=3x3 window per (h,w).
// One block per batch; no atomics (thread 0 writes sums[b]).
// ---------------------------------------------------------------------------
__global__ __launch_bounds__(256) void tps_grid_kernel(
    const float* __restrict__ geo,
    const float* __restrict__ corr,
    float2* __restrict__ gxy,
    float* __restrict__ sums)
{
    const int b   = blockIdx.x;
    const int tid = threadIdx.x;

    __shared__ double sA[12][14];
    __shared__ double sdx[9], sdy[9];
    __shared__ double s_fac[12];
    __shared__ double s_pinv;
    __shared__ int    s_piv;
    __shared__ float  s_wx[9], s_wy[9], s_ax[3], s_ay[3], s_px[9], s_py[9];
    __shared__ float  s_part[4];

    // ---- build system (parallel) ----
    if (tid < 9) {
        float mvx = geo[(b * 9 + tid) * 2 + 0];
        float mvy = geo[(b * 9 + tid) * 2 + 1];
        const float srcx[9] = {0.f, 0.5f, 1.f, 0.f, 0.5f, 1.f, 0.f, 5.f, 1.f};
        const float srcy[9] = {0.f, 0.f,  0.f, 0.5f,0.5f, 0.5f,1.f, 1.f, 1.f};
        sdx[tid] = (double)srcx[tid] + (double)mvx;
        sdy[tid] = (double)srcy[tid] + (double)mvy;
        sA[tid][12] = -(double)mvx;     // delta = src - dst = -mv
        sA[tid][13] = -(double)mvy;
    }
    __syncthreads();
    if (tid < 81) {                      // U block
        int r = tid / 9, c = tid % 9;
        double dx = sdx[r] - sdx[c];
        double dy = sdy[r] - sdy[c];
        double rr = sqrt(dx * dx + dy * dy);
        sA[r][c] = rr * rr * log(rr + 1e-6);
    } else if (tid < 90) {               // P and P^T
        int k = tid - 81;
        sA[k][9]  = 1.0; sA[k][10] = sdx[k]; sA[k][11] = sdy[k];
        sA[9][k]  = 1.0; sA[10][k] = sdx[k]; sA[11][k] = sdy[k];
    } else if (tid < 105) {              // zero block rows 9..11, cols 9..13
        int t = tid - 90;
        sA[9 + t / 5][9 + t % 5] = 0.0;
    }
    __syncthreads();

    // ---- Gauss-Jordan with partial pivoting (parallel) ----
    for (int col = 0; col < 12; ++col) {
        if (tid == 0) {
            int piv = col; double best = fabs(sA[col][col]);
            for (int r = col + 1; r < 12; ++r) {
                double v = fabs(sA[r][col]);
                if (v > best) { best = v; piv = r; }
            }
            s_piv = piv;
        }
        __syncthreads();
        int piv = s_piv;
        if (piv != col && tid < 14) {
            double t = sA[col][tid]; sA[col][tid] = sA[piv][tid]; sA[piv][tid] = t;
        }
        __syncthreads();
        if (tid == 0) s_pinv = 1.0 / sA[col][col];
        __syncthreads();
        if (tid < 14) sA[col][tid] *= s_pinv;
        __syncthreads();
        if (tid < 12) s_fac[tid] = sA[tid][col];
        __syncthreads();
        if (tid < 168) {
            int r = tid / 14, c = tid % 14;
            if (r != col) sA[r][c] -= s_fac[r] * sA[col][c];
        }
        __syncthreads();
    }

    if (tid == 0) {
        double swx = 0.0, swy = 0.0;
        for (int k = 1; k < 9; ++k) { swx += sA[k][12]; swy += sA[k][13]; }
        s_wx[0] = (float)(-swx); s_wy[0] = (float)(-swy);
        for (int k = 1; k < 9; ++k) {
            s_wx[k] = (float)sA[k][12];
            s_wy[k] = (float)sA[k][13];
        }
        s_ax[0] = (float)sA[9][12];  s_ax[1] = (float)sA[10][12]; s_ax[2] = (float)sA[11][12];
        s_ay[0] = (float)sA[9][13];  s_ay[1] = (float)sA[10][13]; s_ay[2] = (float)sA[11][13];
        for (int k = 0; k < 9; ++k) { s_px[k] = (float)sdx[k]; s_py[k] = (float)sdy[k]; }
    }
    __syncthreads();

    // ---- grid eval (f32) + sparse window sum ----
    const float* corr_b = corr + (size_t)b * CORR_PER_B;
    float lsum = 0.0f;
    for (int p = tid; p < GRID_PER_B; p += 256) {
        int h = p / HW, w = p % HW;
        float x = (float)w * (1.0f / 47.0f);
        float y = (float)h * (1.0f / 47.0f);
        float zx = s_ax[0] + s_ax[1] * x + s_ax[2] * y;
        float zy = s_ay[0] + s_ay[1] * x + s_ay[2] * y;
        #pragma unroll
        for (int k = 0; k < 9; ++k) {
            float ddx = x - s_px[k], ddy = y - s_py[k];
            float r2 = ddx * ddx + ddy * ddy;
            float u  = r2 * logf(sqrtf(r2) + 1e-6f);
            zx += s_wx[k] * u;
            zy += s_wy[k] * u;
        }
        float gx = (zx + x) * 47.0f;
        float gy = (zy + y) * 47.0f;
        gxy[b * GRID_PER_B + p] = make_float2(gx, gy);

        // window sum: i tests against gx, j tests against gy (same as kernel 2)
        int ifl = (int)floorf(gx);
        int jfl = (int)floorf(gy);
        for (int dj = -1; dj <= 2; ++dj) {
            int j = jfl + dj;
            if (j < 0 || j > 47) continue;
            if (fabsf((float)j - gy) > 1.0f) continue;
            for (int di = -1; di <= 2; ++di) {
                int i = ifl + di;
                if (i < 0 || i > 47) continue;
                if (fabsf((float)i - gx) > 1.0f) continue;
                lsum += corr_b[(j * HW + i) * GRID_PER_B + p];
            }
        }
    }
    // block reduce -> sums[b]
    for (int off = 32; off > 0; off >>= 1)
        lsum += __shfl_down(lsum, off, 64);
    const int lane = tid & 63, wv = tid >> 6;
    if (lane == 0) s_part[wv] = lsum;
    __syncthreads();
    if (tid == 0) sums[b] = s_part[0] + s_part[1] + s_part[2] + s_part[3];
}

// ---------------------------------------------------------------------------
// Kernel 2: pure masked-copy stream. 8 outputs per thread (2x NT dwordx4
// stores); corr read ONLY where the mask passes. No LDS / barriers / atomics.
// ---------------------------------------------------------------------------
__global__ __launch_bounds__(256) void mask_apply_kernel(
    const float* __restrict__ corr,
    const float2* __restrict__ gxy,
    float* __restrict__ out)
{
    const int e = (blockIdx.x * 256 + threadIdx.x) * 8;

    int w  = e % 48;            // multiple of 8; 8 elems stay in-row
    int t1 = e / 48;
    int h  = t1 % 48;
    int t2 = t1 / 48;
    int i  = t2 % 48;
    int t3 = t2 / 48;
    int j  = t3 % 48;
    int b  = t3 / 48;

    const float fi = (float)i, fj = (float)j;
    const f32x4* g4 = reinterpret_cast<const f32x4*>(gxy + (b * GRID_PER_B + h * HW + w));
    f32x4 ga = g4[0], gb = g4[1], gc = g4[2], gd = g4[3];

    float gx[8] = {ga.x, ga.z, gb.x, gb.z, gc.x, gc.z, gd.x, gd.z};
    float gy[8] = {ga.y, ga.w, gb.y, gb.w, gc.y, gc.w, gd.y, gd.w};

    float v[8];
    #pragma unroll
    for (int c = 0; c < 8; ++c) {
        bool cond = (fabsf(fi - gx[c]) <= 1.0f) && (fabsf(fj - gy[c]) <= 1.0f);
        v[c] = 0.0f;
        if (cond) v[c] = corr[e + c];
    }
    f32x4* o = reinterpret_cast<f32x4*>(out + e);
    f32x4 lo = {v[0], v[1], v[2], v[3]};
    f32x4 hi = {v[4], v[5], v[6], v[7]};
    __builtin_nontemporal_store(lo, o);
    __builtin_nontemporal_store(hi, o + 1);
}

extern "C" void kernel_launch(void* const* d_in, const int* in_sizes, int n_in,
                              void* d_out, int out_size, void* d_ws, size_t ws_size,
                              hipStream_t stream)
{
    const float* geo  = (const float*)d_in[0];   // (B, 9, 2) f32
    const float* corr = (const float*)d_in[1];   // (B, 48, 48, 48, 48) f32

    const int B = in_sizes[0] / 18;              // 8
    const int N = in_sizes[1];                   // B * 48^4

    float*  out  = (float*)d_out;
    float*  sums = out + N;                      // last B elements of d_out
    float2* gxy  = (float2*)d_ws;                // B*2304 float2 = 147 KB

    hipLaunchKernelGGL(tps_grid_kernel, dim3(B), dim3(256), 0, stream,
                       geo, corr, gxy, sums);

    const int nblocks = N / (256 * 8);           // 20736 for B=8
    hipLaunchKernelGGL(mask_apply_kernel, dim3(nblocks), dim3(256), 0, stream,
                       corr, gxy, out);
}

// Round 8
// 311.910 us; speedup vs baseline: 2.0745x; 1.0896x over previous
//
#include <hip/hip_runtime.h>

#define HW 48
#define GRID_PER_B (HW * HW)     // 2304
#define CORR_PER_B (HW * HW * HW * HW)

typedef float f32x4 __attribute__((ext_vector_type(4)));

// ---------------------------------------------------------------------------
// Kernel 1: per-batch TPS fit in LDS (parallel f64 Gauss-Jordan w/ pivoting)
// + grid evaluation (f32, matching reference). One block per batch.
// Writes (gx, gy) per (b,h,w) to d_ws. Nothing else.
// ---------------------------------------------------------------------------
__global__ __launch_bounds__(256) void tps_grid_kernel(
    const float* __restrict__ geo,
    float2* __restrict__ gxy)
{
    const int b   = blockIdx.x;
    const int tid = threadIdx.x;

    __shared__ double sA[12][14];
    __shared__ double sdx[9], sdy[9];
    __shared__ double s_fac[12];
    __shared__ double s_pinv;
    __shared__ int    s_piv;
    __shared__ float  s_wx[9], s_wy[9], s_ax[3], s_ay[3], s_px[9], s_py[9];

    // ---- build system (parallel) ----
    if (tid < 9) {
        float mvx = geo[(b * 9 + tid) * 2 + 0];
        float mvy = geo[(b * 9 + tid) * 2 + 1];
        const float srcx[9] = {0.f, 0.5f, 1.f, 0.f, 0.5f, 1.f, 0.f, 5.f, 1.f};
        const float srcy[9] = {0.f, 0.f,  0.f, 0.5f,0.5f, 0.5f,1.f, 1.f, 1.f};
        sdx[tid] = (double)srcx[tid] + (double)mvx;
        sdy[tid] = (double)srcy[tid] + (double)mvy;
        sA[tid][12] = -(double)mvx;     // delta = src - dst = -mv
        sA[tid][13] = -(double)mvy;
    }
    __syncthreads();
    if (tid < 81) {                      // U block
        int r = tid / 9, c = tid % 9;
        double dx = sdx[r] - sdx[c];
        double dy = sdy[r] - sdy[c];
        double rr = sqrt(dx * dx + dy * dy);
        sA[r][c] = rr * rr * log(rr + 1e-6);
    } else if (tid < 90) {               // P and P^T
        int k = tid - 81;
        sA[k][9]  = 1.0; sA[k][10] = sdx[k]; sA[k][11] = sdy[k];
        sA[9][k]  = 1.0; sA[10][k] = sdx[k]; sA[11][k] = sdy[k];
    } else if (tid < 105) {              // zero block rows 9..11, cols 9..13
        int t = tid - 90;
        sA[9 + t / 5][9 + t % 5] = 0.0;
    }
    __syncthreads();

    // ---- Gauss-Jordan with partial pivoting (parallel) ----
    for (int col = 0; col < 12; ++col) {
        if (tid == 0) {
            int piv = col; double best = fabs(sA[col][col]);
            for (int r = col + 1; r < 12; ++r) {
                double v = fabs(sA[r][col]);
                if (v > best) { best = v; piv = r; }
            }
            s_piv = piv;
        }
        __syncthreads();
        int piv = s_piv;
        if (piv != col && tid < 14) {
            double t = sA[col][tid]; sA[col][tid] = sA[piv][tid]; sA[piv][tid] = t;
        }
        __syncthreads();
        if (tid == 0) s_pinv = 1.0 / sA[col][col];
        __syncthreads();
        if (tid < 14) sA[col][tid] *= s_pinv;
        __syncthreads();
        if (tid < 12) s_fac[tid] = sA[tid][col];
        __syncthreads();
        if (tid < 168) {
            int r = tid / 14, c = tid % 14;
            if (r != col) sA[r][c] -= s_fac[r] * sA[col][c];
        }
        __syncthreads();
    }

    if (tid == 0) {
        double swx = 0.0, swy = 0.0;
        for (int k = 1; k < 9; ++k) { swx += sA[k][12]; swy += sA[k][13]; }
        s_wx[0] = (float)(-swx); s_wy[0] = (float)(-swy);
        for (int k = 1; k < 9; ++k) {
            s_wx[k] = (float)sA[k][12];
            s_wy[k] = (float)sA[k][13];
        }
        s_ax[0] = (float)sA[9][12];  s_ax[1] = (float)sA[10][12]; s_ax[2] = (float)sA[11][12];
        s_ay[0] = (float)sA[9][13];  s_ay[1] = (float)sA[10][13]; s_ay[2] = (float)sA[11][13];
        for (int k = 0; k < 9; ++k) { s_px[k] = (float)sdx[k]; s_py[k] = (float)sdy[k]; }
    }
    __syncthreads();

    // ---- grid eval (f32) ----
    for (int p = tid; p < GRID_PER_B; p += 256) {
        int h = p / HW, w = p % HW;
        float x = (float)w * (1.0f / 47.0f);
        float y = (float)h * (1.0f / 47.0f);
        float zx = s_ax[0] + s_ax[1] * x + s_ax[2] * y;
        float zy = s_ay[0] + s_ay[1] * x + s_ay[2] * y;
        #pragma unroll
        for (int k = 0; k < 9; ++k) {
            float ddx = x - s_px[k], ddy = y - s_py[k];
            float r2 = ddx * ddx + ddy * ddy;
            float u  = r2 * logf(sqrtf(r2) + 1e-6f);
            zx += s_wx[k] * u;
            zy += s_wy[k] * u;
        }
        gxy[b * GRID_PER_B + p] = make_float2((zx + x) * 47.0f, (zy + y) * 47.0f);
    }
}

// ---------------------------------------------------------------------------
// Kernel 2: masked-copy stream. 4 outputs per thread -> ONE lane-contiguous
// NT dwordx4 store (fillBuffer-style full-burst pattern). corr read only
// where mask passes. Per-WAVE partial sums to d_ws (no atomics, no barriers).
// ---------------------------------------------------------------------------
__global__ __launch_bounds__(256) void mask_apply_kernel(
    const float* __restrict__ corr,
    const float2* __restrict__ gxy,
    float* __restrict__ out,
    float* __restrict__ partials)
{
    const int t = blockIdx.x * 256 + threadIdx.x;
    const int e = t * 4;

    int w  = e % 48;            // multiple of 4; 4 elems stay in-row
    int t1 = e / 48;
    int h  = t1 % 48;
    int t2 = t1 / 48;
    int i  = t2 % 48;
    int t3 = t2 / 48;
    int j  = t3 % 48;
    int b  = t3 / 48;

    const float fi = (float)i, fj = (float)j;
    const f32x4* g4 = reinterpret_cast<const f32x4*>(gxy + (b * GRID_PER_B + h * HW + w));
    f32x4 g01 = g4[0], g23 = g4[1];

    float gx[4] = {g01.x, g01.z, g23.x, g23.z};
    float gy[4] = {g01.y, g01.w, g23.y, g23.w};

    float v[4];
    float lsum = 0.0f;
    #pragma unroll
    for (int c = 0; c < 4; ++c) {
        bool cond = (fabsf(fi - gx[c]) <= 1.0f) && (fabsf(fj - gy[c]) <= 1.0f);
        v[c] = 0.0f;
        if (cond) v[c] = corr[e + c];
        lsum += v[c];
    }
    f32x4 val = {v[0], v[1], v[2], v[3]};
    __builtin_nontemporal_store(val, reinterpret_cast<f32x4*>(out + e));

    // wave-level reduction, one coalesced partial write per wave (no atomics)
    for (int off = 32; off > 0; off >>= 1)
        lsum += __shfl_down(lsum, off, 64);
    if ((threadIdx.x & 63) == 0)
        partials[t >> 6] = lsum;     // waves never straddle a batch
}

// ---------------------------------------------------------------------------
// Kernel 3: reduce per-wave partials -> sums[b]. One block per batch.
// ---------------------------------------------------------------------------
__global__ __launch_bounds__(256) void reduce_kernel(
    const float* __restrict__ partials,
    float* __restrict__ sums,
    int waves_per_b)
{
    const int b   = blockIdx.x;
    const int tid = threadIdx.x;
    __shared__ float s_part[4];

    float s = 0.0f;
    for (int k = tid; k < waves_per_b; k += 256)
        s += partials[b * waves_per_b + k];

    for (int off = 32; off > 0; off >>= 1)
        s += __shfl_down(s, off, 64);
    const int lane = tid & 63, wv = tid >> 6;
    if (lane == 0) s_part[wv] = s;
    __syncthreads();
    if (tid == 0) sums[b] = s_part[0] + s_part[1] + s_part[2] + s_part[3];
}

extern "C" void kernel_launch(void* const* d_in, const int* in_sizes, int n_in,
                              void* d_out, int out_size, void* d_ws, size_t ws_size,
                              hipStream_t stream)
{
    const float* geo  = (const float*)d_in[0];   // (B, 9, 2) f32
    const float* corr = (const float*)d_in[1];   // (B, 48, 48, 48, 48) f32

    const int B = in_sizes[0] / 18;              // 8
    const int N = in_sizes[1];                   // B * 48^4

    float*  out      = (float*)d_out;
    float*  sums     = out + N;                  // last B elements of d_out
    float2* gxy      = (float2*)d_ws;            // B*2304 float2 = 147 KB
    float*  partials = (float*)d_ws + 2 * B * GRID_PER_B;  // N/256 floats

    hipLaunchKernelGGL(tps_grid_kernel, dim3(B), dim3(256), 0, stream,
                       geo, gxy);

    const int nblocks = N / (256 * 4);           // 41472 for B=8
    hipLaunchKernelGGL(mask_apply_kernel, dim3(nblocks), dim3(256), 0, stream,
                       corr, gxy, out, partials);

    const int waves_per_b = (N / B) / 256;       // 20736
    hipLaunchKernelGGL(reduce_kernel, dim3(B), dim3(256), 0, stream,
                       partials, sums, waves_per_b);
}

// Round 10
// 281.593 us; speedup vs baseline: 2.2979x; 1.1077x over previous
//
#include <hip/hip_runtime.h>

#define HW 48
#define GRID_PER_B (HW * HW)     // 2304
#define CORR_PER_B (HW * HW * HW * HW)

typedef float f32x4 __attribute__((ext_vector_type(4)));

// ---------------------------------------------------------------------------
// Kernel A: zero-fill the ENTIRE output (incl. the 8 sum slots) — pure
// fillBuffer-style grid-stride dwordx4 stream, nothing else in the kernel.
// ---------------------------------------------------------------------------
__global__ __launch_bounds__(256) void fill_zero_kernel(
    f32x4* __restrict__ out4, int n4)
{
    const int stride = gridDim.x * 256;
    const f32x4 z = {0.0f, 0.0f, 0.0f, 0.0f};
    for (int idx = blockIdx.x * 256 + threadIdx.x; idx < n4; idx += stride)
        out4[idx] = z;
}

// ---------------------------------------------------------------------------
// Kernel B: per-batch TPS fit in LDS (parallel f64 Gauss-Jordan w/ pivoting)
// + grid evaluation (f32, matching reference). One block per batch.
// ---------------------------------------------------------------------------
__global__ __launch_bounds__(256) void tps_grid_kernel(
    const float* __restrict__ geo,
    float2* __restrict__ gxy)
{
    const int b   = blockIdx.x;
    const int tid = threadIdx.x;

    __shared__ double sA[12][14];
    __shared__ double sdx[9], sdy[9];
    __shared__ double s_fac[12];
    __shared__ double s_pinv;
    __shared__ int    s_piv;
    __shared__ float  s_wx[9], s_wy[9], s_ax[3], s_ay[3], s_px[9], s_py[9];

    if (tid < 9) {
        float mvx = geo[(b * 9 + tid) * 2 + 0];
        float mvy = geo[(b * 9 + tid) * 2 + 1];
        const float srcx[9] = {0.f, 0.5f, 1.f, 0.f, 0.5f, 1.f, 0.f, 5.f, 1.f};
        const float srcy[9] = {0.f, 0.f,  0.f, 0.5f,0.5f, 0.5f,1.f, 1.f, 1.f};
        sdx[tid] = (double)srcx[tid] + (double)mvx;
        sdy[tid] = (double)srcy[tid] + (double)mvy;
        sA[tid][12] = -(double)mvx;     // delta = src - dst = -mv
        sA[tid][13] = -(double)mvy;
    }
    __syncthreads();
    if (tid < 81) {                      // U block
        int r = tid / 9, c = tid % 9;
        double dx = sdx[r] - sdx[c];
        double dy = sdy[r] - sdy[c];
        double rr = sqrt(dx * dx + dy * dy);
        sA[r][c] = rr * rr * log(rr + 1e-6);
    } else if (tid < 90) {               // P and P^T
        int k = tid - 81;
        sA[k][9]  = 1.0; sA[k][10] = sdx[k]; sA[k][11] = sdy[k];
        sA[9][k]  = 1.0; sA[10][k] = sdx[k]; sA[11][k] = sdy[k];
    } else if (tid < 105) {              // zero rows 9..11 x cols 9..13
        int t = tid - 90;
        sA[9 + t / 5][9 + t % 5] = 0.0;
    }
    __syncthreads();

    for (int col = 0; col < 12; ++col) {
        if (tid == 0) {
            int piv = col; double best = fabs(sA[col][col]);
            for (int r = col + 1; r < 12; ++r) {
                double v = fabs(sA[r][col]);
                if (v > best) { best = v; piv = r; }
            }
            s_piv = piv;
        }
        __syncthreads();
        int piv = s_piv;
        if (piv != col && tid < 14) {
            double t = sA[col][tid]; sA[col][tid] = sA[piv][tid]; sA[piv][tid] = t;
        }
        __syncthreads();
        if (tid == 0) s_pinv = 1.0 / sA[col][col];
        __syncthreads();
        if (tid < 14) sA[col][tid] *= s_pinv;
        __syncthreads();
        if (tid < 12) s_fac[tid] = sA[tid][col];
        __syncthreads();
        if (tid < 168) {
            int r = tid / 14, c = tid % 14;
            if (r != col) sA[r][c] -= s_fac[r] * sA[col][c];
        }
        __syncthreads();
    }

    if (tid == 0) {
        double swx = 0.0, swy = 0.0;
        for (int k = 1; k < 9; ++k) { swx += sA[k][12]; swy += sA[k][13]; }
        s_wx[0] = (float)(-swx); s_wy[0] = (float)(-swy);
        for (int k = 1; k < 9; ++k) {
            s_wx[k] = (float)sA[k][12];
            s_wy[k] = (float)sA[k][13];
        }
        s_ax[0] = (float)sA[9][12];  s_ax[1] = (float)sA[10][12]; s_ax[2] = (float)sA[11][12];
        s_ay[0] = (float)sA[9][13];  s_ay[1] = (float)sA[10][13]; s_ay[2] = (float)sA[11][13];
        for (int k = 0; k < 9; ++k) { s_px[k] = (float)sdx[k]; s_py[k] = (float)sdy[k]; }
    }
    __syncthreads();

    for (int p = tid; p < GRID_PER_B; p += 256) {
        int h = p / HW, w = p % HW;
        float x = (float)w * (1.0f / 47.0f);
        float y = (float)h * (1.0f / 47.0f);
        float zx = s_ax[0] + s_ax[1] * x + s_ax[2] * y;
        float zy = s_ay[0] + s_ay[1] * x + s_ay[2] * y;
        #pragma unroll
        for (int k = 0; k < 9; ++k) {
            float ddx = x - s_px[k], ddy = y - s_py[k];
            float r2 = ddx * ddx + ddy * ddy;
            float u  = r2 * logf(sqrtf(r2) + 1e-6f);
            zx += s_wx[k] * u;
            zy += s_wy[k] * u;
        }
        gxy[b * GRID_PER_B + p] = make_float2((zx + x) * 47.0f, (zy + y) * 47.0f);
    }
}

// ---------------------------------------------------------------------------
// Kernel C: sparse scatter + sum. One thread per (b, h, w); grid (B, 9).
// Gathers the <=9 in-window corr values (i vs gx, j vs gy — exact float
// compare as the reference), writes them into the zero-filled out, and
// accumulates the per-batch sum (block reduce -> 72 atomicAdds total).
// Candidate set {floor-1, floor, floor+1} is provably a superset of
// {int k : |k - g| <= 1} for non-integer and integer g alike.
// ---------------------------------------------------------------------------
__global__ __launch_bounds__(256) void scatter_sum_kernel(
    const float* __restrict__ corr,
    const float2* __restrict__ gxy,
    float* __restrict__ out,
    float* __restrict__ sums)
{
    const int b   = blockIdx.x;
    const int tid = threadIdx.x;
    const int p   = blockIdx.y * 256 + tid;      // (h*48 + w), 9*256 = 2304

    float2 g = gxy[b * GRID_PER_B + p];
    const float* corr_b = corr + (size_t)b * CORR_PER_B;
    float*       out_b  = out  + (size_t)b * CORR_PER_B;

    const int ifl = (int)floorf(g.x);
    const int jfl = (int)floorf(g.y);

    float lsum = 0.0f;
    #pragma unroll
    for (int dj = -1; dj <= 1; ++dj) {
        int j = jfl + dj;
        if (j < 0 || j > 47) continue;
        if (fabsf((float)j - g.y) > 1.0f) continue;
        #pragma unroll
        for (int di = -1; di <= 1; ++di) {
            int i = ifl + di;
            if (i < 0 || i > 47) continue;
            if (fabsf((float)i - g.x) > 1.0f) continue;
            int ofs = (j * HW + i) * GRID_PER_B + p;
            float v = corr_b[ofs];
            out_b[ofs] = v;
            lsum += v;
        }
    }

    for (int off = 32; off > 0; off >>= 1)
        lsum += __shfl_down(lsum, off, 64);
    __shared__ float parts[4];
    if ((tid & 63) == 0) parts[tid >> 6] = lsum;
    __syncthreads();
    if (tid == 0)
        atomicAdd(&sums[b], parts[0] + parts[1] + parts[2] + parts[3]);
}

extern "C" void kernel_launch(void* const* d_in, const int* in_sizes, int n_in,
                              void* d_out, int out_size, void* d_ws, size_t ws_size,
                              hipStream_t stream)
{
    const float* geo  = (const float*)d_in[0];   // (B, 9, 2) f32
    const float* corr = (const float*)d_in[1];   // (B, 48, 48, 48, 48) f32

    const int B = in_sizes[0] / 18;              // 8
    const int N = in_sizes[1];                   // B * 48^4

    float*  out  = (float*)d_out;
    float*  sums = out + N;                      // last B elements of d_out
    float2* gxy  = (float2*)d_ws;                // B*2304 float2 = 147 KB

    // A: zero-fill full output (out_size = N + B, divisible by 4)
    const int n4 = out_size / 4;
    hipLaunchKernelGGL(fill_zero_kernel, dim3(2048), dim3(256), 0, stream,
                       (f32x4*)d_out, n4);

    // B: TPS fit + warp grid
    hipLaunchKernelGGL(tps_grid_kernel, dim3(B), dim3(256), 0, stream,
                       geo, gxy);

    // C: sparse scatter + per-batch sums (needs A for zeros, B for gxy)
    hipLaunchKernelGGL(scatter_sum_kernel, dim3(B, GRID_PER_B / 256), dim3(256),
                       0, stream, corr, gxy, out, sums);
}

// Round 12
// 274.328 us; speedup vs baseline: 2.3587x; 1.0265x over previous
//
#include <hip/hip_runtime.h>

#define HW 48
#define GRID_PER_B (HW * HW)     // 2304
#define CORR_PER_B (HW * HW * HW * HW)

typedef float f32x4 __attribute__((ext_vector_type(4)));

// ---------------------------------------------------------------------------
// Kernel A: zero-fill the ENTIRE output (incl. the 8 sum slots) — pure
// fillBuffer-style grid-stride dwordx4 stream.
// ---------------------------------------------------------------------------
__global__ __launch_bounds__(256) void fill_zero_kernel(
    f32x4* __restrict__ out4, int n4)
{
    const int stride = gridDim.x * 256;
    const f32x4 z = {0.0f, 0.0f, 0.0f, 0.0f};
    for (int idx = blockIdx.x * 256 + threadIdx.x; idx < n4; idx += stride)
        out4[idx] = z;
}

// ---------------------------------------------------------------------------
// Kernel B: fused TPS-solve + grid-eval + sparse scatter + sum.
// Grid (B, 9), 256 threads. Each block redoes the (cheap) 12x12 f64
// Gauss-Jordan solve in LDS for its batch, evaluates its 256 (h,w) grid
// points in-register, gathers the <=9 in-window corr values (exact float
// compares identical to the reference), scatters them into the zero-filled
// out, and contributes one atomicAdd to sums[b] (72 atomics total).
// Candidate set {floor-1, floor, floor+1} is a superset of
// {int k : |k - g| <= 1} for any g.
// ---------------------------------------------------------------------------
__global__ __launch_bounds__(256) void tps_scatter_kernel(
    const float* __restrict__ geo,
    const float* __restrict__ corr,
    float* __restrict__ out,
    float* __restrict__ sums)
{
    const int b   = blockIdx.x;
    const int tid = threadIdx.x;

    __shared__ double sA[12][14];
    __shared__ double sdx[9], sdy[9];
    __shared__ double s_fac[12];
    __shared__ double s_pinv;
    __shared__ int    s_piv;
    __shared__ float  s_wx[9], s_wy[9], s_ax[3], s_ay[3], s_px[9], s_py[9];

    // ---- build system (parallel) ----
    if (tid < 9) {
        float mvx = geo[(b * 9 + tid) * 2 + 0];
        float mvy = geo[(b * 9 + tid) * 2 + 1];
        const float srcx[9] = {0.f, 0.5f, 1.f, 0.f, 0.5f, 1.f, 0.f, 5.f, 1.f};
        const float srcy[9] = {0.f, 0.f,  0.f, 0.5f,0.5f, 0.5f,1.f, 1.f, 1.f};
        sdx[tid] = (double)srcx[tid] + (double)mvx;
        sdy[tid] = (double)srcy[tid] + (double)mvy;
        sA[tid][12] = -(double)mvx;     // delta = src - dst = -mv
        sA[tid][13] = -(double)mvy;
    }
    __syncthreads();
    if (tid < 81) {                      // U block
        int r = tid / 9, c = tid % 9;
        double dx = sdx[r] - sdx[c];
        double dy = sdy[r] - sdy[c];
        double rr = sqrt(dx * dx + dy * dy);
        sA[r][c] = rr * rr * log(rr + 1e-6);
    } else if (tid < 90) {               // P and P^T
        int k = tid - 81;
        sA[k][9]  = 1.0; sA[k][10] = sdx[k]; sA[k][11] = sdy[k];
        sA[9][k]  = 1.0; sA[10][k] = sdx[k]; sA[11][k] = sdy[k];
    } else if (tid < 105) {              // zero rows 9..11 x cols 9..13
        int t = tid - 90;
        sA[9 + t / 5][9 + t % 5] = 0.0;
    }
    __syncthreads();

    // ---- Gauss-Jordan with partial pivoting (parallel) ----
    for (int col = 0; col < 12; ++col) {
        if (tid == 0) {
            int piv = col; double best = fabs(sA[col][col]);
            for (int r = col + 1; r < 12; ++r) {
                double v = fabs(sA[r][col]);
                if (v > best) { best = v; piv = r; }
            }
            s_piv = piv;
        }
        __syncthreads();
        int piv = s_piv;
        if (piv != col && tid < 14) {
            double t = sA[col][tid]; sA[col][tid] = sA[piv][tid]; sA[piv][tid] = t;
        }
        __syncthreads();
        if (tid == 0) s_pinv = 1.0 / sA[col][col];
        __syncthreads();
        if (tid < 14) sA[col][tid] *= s_pinv;
        __syncthreads();
        if (tid < 12) s_fac[tid] = sA[tid][col];
        __syncthreads();
        if (tid < 168) {
            int r = tid / 14, c = tid % 14;
            if (r != col) sA[r][c] -= s_fac[r] * sA[col][c];
        }
        __syncthreads();
    }

    if (tid == 0) {
        double swx = 0.0, swy = 0.0;
        for (int k = 1; k < 9; ++k) { swx += sA[k][12]; swy += sA[k][13]; }
        s_wx[0] = (float)(-swx); s_wy[0] = (float)(-swy);
        for (int k = 1; k < 9; ++k) {
            s_wx[k] = (float)sA[k][12];
            s_wy[k] = (float)sA[k][13];
        }
        s_ax[0] = (float)sA[9][12];  s_ax[1] = (float)sA[10][12]; s_ax[2] = (float)sA[11][12];
        s_ay[0] = (float)sA[9][13];  s_ay[1] = (float)sA[10][13]; s_ay[2] = (float)sA[11][13];
        for (int k = 0; k < 9; ++k) { s_px[k] = (float)sdx[k]; s_py[k] = (float)sdy[k]; }
    }
    __syncthreads();

    // ---- grid eval (f32, identical arithmetic to reference) ----
    const int p = blockIdx.y * 256 + tid;        // h*48 + w
    const int h = p / HW, w = p % HW;
    {
        float x = (float)w * (1.0f / 47.0f);
        float y = (float)h * (1.0f / 47.0f);
        float zx = s_ax[0] + s_ax[1] * x + s_ax[2] * y;
        float zy = s_ay[0] + s_ay[1] * x + s_ay[2] * y;
        #pragma unroll
        for (int k = 0; k < 9; ++k) {
            float ddx = x - s_px[k], ddy = y - s_py[k];
            float r2 = ddx * ddx + ddy * ddy;
            float u  = r2 * logf(sqrtf(r2) + 1e-6f);
            zx += s_wx[k] * u;
            zy += s_wy[k] * u;
        }
        float gx = (zx + x) * 47.0f;
        float gy = (zy + y) * 47.0f;

        // ---- sparse window scatter + sum ----
        const float* corr_b = corr + (size_t)b * CORR_PER_B;
        float*       out_b  = out  + (size_t)b * CORR_PER_B;
        const int ifl = (int)floorf(gx);
        const int jfl = (int)floorf(gy);

        float lsum = 0.0f;
        #pragma unroll
        for (int dj = -1; dj <= 1; ++dj) {
            int j = jfl + dj;
            if (j < 0 || j > 47) continue;
            if (fabsf((float)j - gy) > 1.0f) continue;
            #pragma unroll
            for (int di = -1; di <= 1; ++di) {
                int i = ifl + di;
                if (i < 0 || i > 47) continue;
                if (fabsf((float)i - gx) > 1.0f) continue;
                int ofs = (j * HW + i) * GRID_PER_B + p;
                float v = corr_b[ofs];
                out_b[ofs] = v;
                lsum += v;
            }
        }

        for (int off = 32; off > 0; off >>= 1)
            lsum += __shfl_down(lsum, off, 64);
        __shared__ float parts[4];
        if ((tid & 63) == 0) parts[tid >> 6] = lsum;
        __syncthreads();
        if (tid == 0)
            atomicAdd(&sums[b], parts[0] + parts[1] + parts[2] + parts[3]);
    }
}

extern "C" void kernel_launch(void* const* d_in, const int* in_sizes, int n_in,
                              void* d_out, int out_size, void* d_ws, size_t ws_size,
                              hipStream_t stream)
{
    const float* geo  = (const float*)d_in[0];   // (B, 9, 2) f32
    const float* corr = (const float*)d_in[1];   // (B, 48, 48, 48, 48) f32

    const int B = in_sizes[0] / 18;              // 8
    const int N = in_sizes[1];                   // B * 48^4

    float* out  = (float*)d_out;
    float* sums = out + N;                       // last B elements of d_out

    // A: zero-fill full output (out_size = N + B, divisible by 4)
    const int n4 = out_size / 4;
    hipLaunchKernelGGL(fill_zero_kernel, dim3(2048), dim3(256), 0, stream,
                       (f32x4*)d_out, n4);

    // B: fused TPS solve + grid eval + sparse scatter + per-batch sums
    hipLaunchKernelGGL(tps_scatter_kernel, dim3(B, GRID_PER_B / 256), dim3(256),
                       0, stream, geo, corr, out, sums);
}